// Round 5
// baseline (909.579 us; speedup 1.0000x reference)
//
#include <hip/hip_runtime.h>

#define H 512
#define MTILE 32
#define NBLK 16384
#define STEPC (2.4f / 63.0f)

typedef _Float16 half8 __attribute__((ext_vector_type(8)));
typedef _Float16 half4_t __attribute__((ext_vector_type(4)));
typedef float floatx16 __attribute__((ext_vector_type(16)));
typedef float floatx4 __attribute__((ext_vector_type(4)));
typedef float floatx2 __attribute__((ext_vector_type(2)));

// fast silu: native exp + fast div. rel-err ~1e-7, negligible vs fp16 rounding.
__device__ inline float silu_f(float x) {
    return __fdividef(x, 1.0f + __expf(-x));
}

// ---- prep 1: lat_part[b][j] = b0[j] + sum_d lat[b][d] * W0[d][j] ----
__global__ void prep_latw(const float* __restrict__ lat, const float* __restrict__ W0,
                          const float* __restrict__ b0, float* __restrict__ latw) {
    __shared__ float sl[H];
    const int b = blockIdx.x;
    const int j = threadIdx.x;
    sl[j] = lat[b * H + j];
    __syncthreads();
    float acc = b0[j];
#pragma unroll 8
    for (int d = 0; d < H; ++d) acc += sl[d] * W0[d * H + j];
    latw[b * H + j] = acc;
}

// ---- prep 2: W1/W2 -> fp16, fragment-major for 32x32x16 (unchanged R4) ----
// lane mapping (first operand): n = lane&31, k = (lane>>5)*8 + e
// image: idx = ((l*64 + (k>>3))*512 + n)*8 + (k&7)
__global__ void prep_w16(const float* __restrict__ W1, const float* __restrict__ W2,
                         _Float16* __restrict__ ws) {
    const int id = blockIdx.x * 512 + threadIdx.x;   // 0 .. 524287
    const int l = id >> 18;
    const int rem = id & 0x3FFFF;                    // k*512 + n
    const int k = rem >> 9, n = rem & 511;
    const float w = (l == 0 ? W1 : W2)[rem];
    ws[((size_t)(l * 64 + (k >> 3)) * 512 + n) * 8 + (k & 7)] = (_Float16)w;
}

// ---- main fused kernel ----
// R5: CONCURRENCY RESHAPE. R1-R4 proved the instruction mix is time-invariant
// (conflicts -9x, VALU -10pts, MFMA count -2x: all ~770us) -> latency-bound
// lockstep structure. Change: 4 INDEPENDENT 4-wave blocks per CU instead of
// 2 barrier-coupled 8-wave blocks.
//   * MTILE 32, 256 threads; LDS 37 KB -> 4 blocks/CU (16 waves/CU, as before,
//     but in 4 desynchronized barrier domains: VALU phases / vmcnt stalls of
//     one block overlap MFMA of the others).
//   * per wave: 32x128 tile = 4 nt of 32x32; per ks: 4 global b128 (W) +
//     1 ds_read_b128 (h) + 4 MFMA. acc = 4 x floatx16 = 64 AGPR.
//   * simple 2-deep double-buffer, no &31 wraps (kills R4's scratch spill;
//     WRITE_SIZE should return to ~2 MB).
//   * h LDS fragment-major: [64 regions][32 rows][8], all reads/writes
//     contiguous, conflict-free; ks folds into ds offset immediates.
__global__ __launch_bounds__(256, 4) void mesh_main(
    const float* __restrict__ W0, const float* __restrict__ b1,
    const float* __restrict__ b2, const float* __restrict__ W3,
    const float* __restrict__ b3, const float* __restrict__ latw,
    const _Float16* __restrict__ wsB, float* __restrict__ out) {

    __shared__ _Float16 hbuf2[2048 * 8];          // 32 KB, fragment-major h
    __shared__ float lwbuf[2 * H];                // 4 KB
    __shared__ float partials[4][MTILE];          // 0.5 KB -> ~36.6 KB total

    const int tid = threadIdx.x;                  // 0..255
    const int wave = tid >> 6, lane = tid & 63;
    const int lm = lane & 31, hi = lane >> 5;
    const int bi = blockIdx.x;
    const int b = bi >> 13;
    const int p0 = (bi & 8191) << 5;              // 32 points per block
    const float c0 = -1.2f + (float)(p0 >> 12) * STEPC;
    const float c1 = -1.2f + (float)((p0 >> 6) & 63) * STEPC;
    const float z0 = -1.2f + (float)(p0 & 63) * STEPC;

    // ---- layer 0, phase A: lw[j] = latw + c0*W0x + c1*W0y; w2c[j] = W0z ----
#pragma unroll
    for (int it = 0; it < 2; ++it) {
        const int j = tid + it * 256;
        const float lwv = latw[b * H + j]
                        + c0 * W0[(H + 0) * H + j]
                        + c1 * W0[(H + 1) * H + j];
        floatx2 v;
        v[0] = lwv;
        v[1] = W0[(H + 2) * H + j];
        *(floatx2*)&lwbuf[2 * j] = v;
    }
    __syncthreads();

    // ---- layer 0, phase B: row = lm; regions g = wave*16 + hi*8 + s ----
    {
        const float c2v = z0 + (float)lm * STEPC;
#pragma unroll
        for (int s = 0; s < 8; ++s) {
            const int g = wave * 16 + hi * 8 + s;
            const floatx4* lp = (const floatx4*)&lwbuf[g * 16];  // broadcast reads
            half8 hv;
#pragma unroll
            for (int i = 0; i < 4; ++i) {
                const floatx4 pv = lp[i];          // (lw, w2c, lw, w2c)
                hv[2 * i + 0] = (_Float16)silu_f(pv[0] + c2v * pv[1]);
                hv[2 * i + 1] = (_Float16)silu_f(pv[2] + c2v * pv[3]);
            }
            *(half8*)&hbuf2[(g * 32 + lm) * 8] = hv;   // contiguous, conflict-free
        }
    }

    // per-lane bases: h (second operand, m = lm) and W (first operand, n)
    const _Float16* hb = hbuf2 + hi * 256 + lm * 8;
    const _Float16* wsl = wsB + ((size_t)hi * 512 + wave * 128 + lm) * 8;

    floatx16 acc[4];                               // nt j = 0..3: 64 AGPR

    auto zero_acc = [&]() {
#pragma unroll
        for (int j = 0; j < 4; ++j)
#pragma unroll
            for (int r = 0; r < 16; ++r) acc[j][r] = 0.f;
    };

    auto loadW = [&](int l, int ks, half8 (&wf)[4]) {
        const _Float16* p = wsl + (size_t)(l * 32 + ks) * 8192;
#pragma unroll
        for (int j = 0; j < 4; ++j)
            wf[j] = *(const half8*)(p + j * 256);  // n + j*32, imm offsets
    };

    auto compute = [&](half8 (&wf)[4], half8 a) {
#pragma unroll
        for (int j = 0; j < 4; ++j)
            acc[j] = __builtin_amdgcn_mfma_f32_32x32x16_f16(wf[j], a, acc[j], 0, 0, 0);
    };

    // double-buffered K-loop, no wrap loads (R4 spill fix)
    auto run_gemm = [&](int l) {
        half8 Wb0[4], Wb1[4], a0, a1;
        loadW(l, 0, Wb0); a0 = *(const half8*)(hb + 0 * 512);
        loadW(l, 1, Wb1); a1 = *(const half8*)(hb + 1 * 512);
#pragma unroll 1
        for (int ks = 0; ks < 30; ks += 2) {
            compute(Wb0, a0);
            loadW(l, ks + 2, Wb0); a0 = *(const half8*)(hb + (ks + 2) * 512);
            compute(Wb1, a1);
            loadW(l, ks + 3, Wb1); a1 = *(const half8*)(hb + (ks + 3) * 512);
        }
        compute(Wb0, a0);
        compute(Wb1, a1);
    };

    // ---- GEMM 1 ----
    zero_acc();
    __syncthreads();             // h0 ready
    run_gemm(0);
    __syncthreads();             // all waves done reading h0
    // writeback h1 = silu(acc + b1): lane owns 4 consecutive n per (j,g):
    // n = wave*128 + j*32 + g*8 + hi*4 .. +3 at row m = lm
    // -> region wave*16 + j*4 + g, element offset hi*4: packed b64, conflict-free
    {
        _Float16* wb = hbuf2 + lm * 8 + hi * 4;
#pragma unroll
        for (int j = 0; j < 4; ++j)
#pragma unroll
            for (int g = 0; g < 4; ++g) {
                const floatx4 b1v = *(const floatx4*)&b1[wave * 128 + j * 32 + g * 8 + hi * 4];
                half4_t hv;
#pragma unroll
                for (int r = 0; r < 4; ++r)
                    hv[r] = (_Float16)silu_f(acc[j][g * 4 + r] + b1v[r]);
                *(half4_t*)(wb + (wave * 16 + j * 4 + g) * 256) = hv;
            }
    }

    // ---- GEMM 2 ----
    zero_acc();
    __syncthreads();             // h1 ready
    run_gemm(1);

    // ---- final layer: out = silu(acc + b2) @ W3 + b3, fp32 VALU ----
    {
        float sum = 0.f;
#pragma unroll
        for (int j = 0; j < 4; ++j)
#pragma unroll
            for (int g = 0; g < 4; ++g) {
                const int n0 = wave * 128 + j * 32 + g * 8 + hi * 4;
                const floatx4 b2v = *(const floatx4*)&b2[n0];
                const floatx4 w3v = *(const floatx4*)&W3[n0];
#pragma unroll
                for (int r = 0; r < 4; ++r)
                    sum += silu_f(acc[j][g * 4 + r] + b2v[r]) * w3v[r];
            }
        sum += __shfl_xor(sum, 32);        // combine hi halves (same m = lm)
        if (hi == 0) partials[wave][lm] = sum;
    }
    __syncthreads();
    if (tid < MTILE) {
        float o = b3[0];
#pragma unroll
        for (int w = 0; w < 4; ++w) o += partials[w][tid];
        out[(size_t)bi * MTILE + tid] = o;
    }
}

extern "C" void kernel_launch(void* const* d_in, const int* in_sizes, int n_in,
                              void* d_out, int out_size, void* d_ws, size_t ws_size,
                              hipStream_t stream) {
    const float* lat = (const float*)d_in[0];
    const float* W0  = (const float*)d_in[1];
    const float* b0  = (const float*)d_in[2];
    const float* W1  = (const float*)d_in[3];
    const float* b1  = (const float*)d_in[4];
    const float* W2  = (const float*)d_in[5];
    const float* b2  = (const float*)d_in[6];
    const float* W3  = (const float*)d_in[7];
    const float* b3  = (const float*)d_in[8];
    float* out = (float*)d_out;

    float* latw = (float*)d_ws;                               // 4 KB
    _Float16* wsB = (_Float16*)((char*)d_ws + 4096);          // 1 MB

    prep_latw<<<2, 512, 0, stream>>>(lat, W0, b0, latw);
    prep_w16<<<1024, 512, 0, stream>>>(W1, W2, wsB);
    mesh_main<<<NBLK, 256, 0, stream>>>(W0, b1, b2, W3, b3, latw, wsB, out);
}

// Round 6
// 810.891 us; speedup vs baseline: 1.1217x; 1.1217x over previous
//
#include <hip/hip_runtime.h>

#define H 512
#define MTILE 64
#define NBLK 8192
#define STEPC (2.4f / 63.0f)

typedef _Float16 half8 __attribute__((ext_vector_type(8)));
typedef _Float16 half4_t __attribute__((ext_vector_type(4)));
typedef float floatx16 __attribute__((ext_vector_type(16)));
typedef float floatx4 __attribute__((ext_vector_type(4)));
typedef float floatx2 __attribute__((ext_vector_type(2)));

// fast silu: native exp + fast div. rel-err ~1e-7, negligible vs fp16 rounding.
__device__ inline float silu_f(float x) {
    return __fdividef(x, 1.0f + __expf(-x));
}

// ---- fused prep: blocks 0..1023 -> W image; blocks 1024..1025 -> latw ----
// W image layout (R6): [l][wv][hi][ks][nt][lm][e]  (halves)
//   idx = (l*8+wv)*32768 + hi*16384 + ks*512 + nt*256 + lm*8 + e
//   -> per-wave base (l,wv) is UNIFORM; per-lane off = hi*16384 + lm*8 is
//      loop-constant; ks*512 + nt*256 advances by SALU/imm only.
__global__ void prep_fused(const float* __restrict__ lat, const float* __restrict__ W0,
                           const float* __restrict__ b0,
                           const float* __restrict__ W1, const float* __restrict__ W2,
                           float* __restrict__ latw, _Float16* __restrict__ ws) {
    __shared__ float sl[H];
    if (blockIdx.x < 1024) {
        const int id = blockIdx.x * 512 + threadIdx.x;   // 0 .. 524287
        const int l = id >> 18;
        const int rem = id & 0x3FFFF;                    // k*512 + n
        const int k = rem >> 9, n = rem & 511;
        const float w = (l == 0 ? W1 : W2)[rem];
        const int ks = k >> 4, hi = (k >> 3) & 1, e = k & 7;
        const int wv = n >> 6, nt = (n >> 5) & 1, lm = n & 31;
        ws[(size_t)(l * 8 + wv) * 32768 + hi * 16384 + ks * 512 + nt * 256 + lm * 8 + e]
            = (_Float16)w;
    } else {
        const int b = blockIdx.x - 1024;
        const int j = threadIdx.x;
        sl[j] = lat[b * H + j];
        __syncthreads();
        float acc = b0[j];
#pragma unroll 8
        for (int d = 0; d < H; ++d) acc += sl[d] * W0[d * H + j];
        latw[b * H + j] = acc;
    }
}

// ---- main fused kernel ----
// R6: 2 waves/SIMD + deep register prefetch + SALU-addressed W stream.
//   * launch_bounds(512,2): one 8-wave block per CU, 256-reg budget.
//   * K-loop fully unrolled, 6-deep W prefetch (static rotating buffers,
//     rule #20 safe), 3-deep A prefetch from LDS (pure offset-imm ds_reads).
//   * W loads: uniform saddr (readfirstlane'd wave base) + constant voffset
//     + imm -> near-zero per-ks VALU addressing.
//   * layer-0 / epilogues / layouts byte-identical to R4 (verified).
__global__ __launch_bounds__(512, 2) void mesh_main(
    const float* __restrict__ W0, const float* __restrict__ b1,
    const float* __restrict__ b2, const float* __restrict__ W3,
    const float* __restrict__ b3, const float* __restrict__ latw,
    const _Float16* __restrict__ wsB, float* __restrict__ out) {

    __shared__ _Float16 hbuf2[4096 * 8];          // 64 KB, fragment-major h
    __shared__ float lwbuf[2 * H];                // 4 KB
    __shared__ float partials[8][MTILE];          // 2 KB  -> 70 KB total

    const int tid = threadIdx.x;
    const int wave = tid >> 6, lane = tid & 63;
    const int lm = lane & 31, hi = lane >> 5;
    const int uwave = __builtin_amdgcn_readfirstlane(wave);  // force SGPR
    const int bi = blockIdx.x;
    const int b = bi >> 12;
    const int p0 = (bi & 4095) << 6;              // 64 rows per block (fixed x,y)
    const float c0 = -1.2f + (float)(p0 >> 12) * STEPC;
    const float c1 = -1.2f + (float)((p0 >> 6) & 63) * STEPC;

    // ---- layer 0, phase A: lw[j] = latw + c0*W0x + c1*W0y; w2c[j] = W0z ----
    {
        const int j = tid;
        const float lwv = latw[b * H + j]
                        + c0 * W0[(H + 0) * H + j]
                        + c1 * W0[(H + 1) * H + j];
        floatx2 v;
        v[0] = lwv;
        v[1] = W0[(H + 2) * H + j];
        *(floatx2*)&lwbuf[2 * j] = v;
    }
    __syncthreads();

    // ---- layer 0, phase B: row m = lane; regions g = wave*8+s ----
    {
        const float c2v = -1.2f + (float)lane * STEPC;
#pragma unroll
        for (int s = 0; s < 8; ++s) {
            const int g = wave * 8 + s;
            const floatx4* lp = (const floatx4*)&lwbuf[g * 16];  // broadcast reads
            half8 hv;
#pragma unroll
            for (int i = 0; i < 4; ++i) {
                const floatx4 pv = lp[i];          // (lw, w2c, lw, w2c)
                hv[2 * i + 0] = (_Float16)silu_f(pv[0] + c2v * pv[1]);
                hv[2 * i + 1] = (_Float16)silu_f(pv[2] + c2v * pv[3]);
            }
            *(half8*)&hbuf2[(g * 64 + lane) * 8] = hv;
        }
    }

    // per-lane bases
    const _Float16* hb = hbuf2 + hi * 512 + lm * 8;      // A: LDS base, imm offsets
    const int vWoff = hi * 16384 + lm * 8;               // W: loop-constant voffset

    floatx16 acc[2][2];

    auto zero_acc = [&]() {
#pragma unroll
        for (int mb = 0; mb < 2; ++mb)
#pragma unroll
            for (int nt = 0; nt < 2; ++nt)
#pragma unroll
                for (int r = 0; r < 16; ++r) acc[mb][nt][r] = 0.f;
    };

    auto loadW = [&](const _Float16* base, int ks, half8 (&wf)[2]) {
        const _Float16* p = base + vWoff + ks * 512;
        wf[0] = *(const half8*)(p);            // nt=0
        wf[1] = *(const half8*)(p + 256);      // nt=1
    };

    auto loadA = [&](int ks, half8 (&a)[2]) {
        const _Float16* hp = hb + ks * 1024;
        a[0] = *(const half8*)(hp);            // mb=0, pure offset-imm ds_read
        a[1] = *(const half8*)(hp + 256);      // mb=1
    };

    auto compute = [&](half8 (&wf)[2], half8 (&a)[2]) {
#pragma unroll
        for (int nt = 0; nt < 2; ++nt)
#pragma unroll
            for (int mb = 0; mb < 2; ++mb)
                acc[mb][nt] = __builtin_amdgcn_mfma_f32_32x32x16_f16(wf[nt], a[mb], acc[mb][nt], 0, 0, 0);
    };

    // fully-unrolled K-loop: 6-deep W prefetch, 3-deep A prefetch.
    auto run_gemm = [&](const _Float16* base) {
        half8 Wq[6][2];
        half8 Aq[3][2];
#pragma unroll
        for (int i = 0; i < 6; ++i) loadW(base, i, Wq[i]);
#pragma unroll
        for (int i = 0; i < 3; ++i) loadA(i, Aq[i]);
#pragma unroll
        for (int ks = 0; ks < 32; ++ks) {       // all indices static after unroll
            compute(Wq[ks % 6], Aq[ks % 3]);
            if (ks + 6 < 32) loadW(base, ks + 6, Wq[ks % 6]);
            if (ks + 3 < 32) loadA(ks + 3, Aq[ks % 3]);
        }
    };

    const _Float16* wbase0 = wsB + (size_t)uwave * 32768;         // GEMM1 (W1)
    const _Float16* wbase1 = wsB + (size_t)(8 + uwave) * 32768;   // GEMM2 (W2)

    // ---- GEMM 1 ----
    zero_acc();
    __syncthreads();             // h0 ready
    run_gemm(wbase0);
    __syncthreads();             // all waves done reading h0
    // writeback h1 = silu(acc + b1): lane owns, per (mb,nt,g), 4 consecutive
    // n = wave*64 + nt*32 + g*8 + hi*4 .. +3 at row m = mb*32+lm -> b64 writes
    {
        _Float16* wb = hbuf2 + (wave * 8) * 512 + lm * 8 + hi * 4;
        floatx4 b1v[2][4];
#pragma unroll
        for (int nt = 0; nt < 2; ++nt)
#pragma unroll
            for (int g = 0; g < 4; ++g)
                b1v[nt][g] = *(const floatx4*)&b1[wave * 64 + nt * 32 + g * 8 + hi * 4];
#pragma unroll
        for (int mb = 0; mb < 2; ++mb)
#pragma unroll
            for (int nt = 0; nt < 2; ++nt)
#pragma unroll
                for (int g = 0; g < 4; ++g) {
                    half4_t hv;
#pragma unroll
                    for (int j = 0; j < 4; ++j)
                        hv[j] = (_Float16)silu_f(acc[mb][nt][g * 4 + j] + b1v[nt][g][j]);
                    *(half4_t*)(wb + (nt * 4 + g) * 512 + mb * 256) = hv;
                }
    }

    // ---- GEMM 2 ----
    zero_acc();
    __syncthreads();             // h1 ready
    run_gemm(wbase1);

    // ---- final layer: out = silu(acc + b2) @ W3 + b3, fp32 VALU ----
    {
        floatx4 b2v[2][4], w3v[2][4];
#pragma unroll
        for (int nt = 0; nt < 2; ++nt)
#pragma unroll
            for (int g = 0; g < 4; ++g) {
                const int n0 = wave * 64 + nt * 32 + g * 8 + hi * 4;
                b2v[nt][g] = *(const floatx4*)&b2[n0];
                w3v[nt][g] = *(const floatx4*)&W3[n0];
            }
#pragma unroll
        for (int mb = 0; mb < 2; ++mb) {
            float sum = 0.f;
#pragma unroll
            for (int nt = 0; nt < 2; ++nt)
#pragma unroll
                for (int g = 0; g < 4; ++g)
#pragma unroll
                    for (int j = 0; j < 4; ++j)
                        sum += silu_f(acc[mb][nt][g * 4 + j] + b2v[nt][g][j]) * w3v[nt][g][j];
            sum += __shfl_xor(sum, 32);        // combine hi halves (same m)
            if (hi == 0) partials[wave][mb * 32 + lm] = sum;
        }
    }
    __syncthreads();
    if (tid < MTILE) {
        float o = b3[0];
#pragma unroll
        for (int w = 0; w < 8; ++w) o += partials[w][tid];
        out[(size_t)bi * MTILE + tid] = o;
    }
}

extern "C" void kernel_launch(void* const* d_in, const int* in_sizes, int n_in,
                              void* d_out, int out_size, void* d_ws, size_t ws_size,
                              hipStream_t stream) {
    const float* lat = (const float*)d_in[0];
    const float* W0  = (const float*)d_in[1];
    const float* b0  = (const float*)d_in[2];
    const float* W1  = (const float*)d_in[3];
    const float* b1  = (const float*)d_in[4];
    const float* W2  = (const float*)d_in[5];
    const float* b2  = (const float*)d_in[6];
    const float* W3  = (const float*)d_in[7];
    const float* b3  = (const float*)d_in[8];
    float* out = (float*)d_out;

    float* latw = (float*)d_ws;                               // 4 KB
    _Float16* wsB = (_Float16*)((char*)d_ws + 4096);          // 1 MB

    prep_fused<<<1026, 512, 0, stream>>>(lat, W0, b0, W1, W2, latw, wsB);
    mesh_main<<<NBLK, 512, 0, stream>>>(W0, b1, b2, W3, b3, latw, wsB, out);
}

// Round 8
// 781.355 us; speedup vs baseline: 1.1641x; 1.0378x over previous
//
#include <hip/hip_runtime.h>

#define H 512
#define MTILE 64
#define NBLK 8192
#define STEPC (2.4f / 63.0f)

typedef _Float16 half8 __attribute__((ext_vector_type(8)));
typedef _Float16 half4_t __attribute__((ext_vector_type(4)));
typedef float floatx16 __attribute__((ext_vector_type(16)));
typedef float floatx4 __attribute__((ext_vector_type(4)));
typedef float floatx2 __attribute__((ext_vector_type(2)));

// fast silu: native exp + fast div. rel-err ~1e-7, negligible vs fp16 rounding.
__device__ inline float silu_f(float x) {
    return __fdividef(x, 1.0f + __expf(-x));
}

// ---- fused prep: blocks 0..1023 -> W image; blocks 1024..1025 -> latw ----
// W image layout: [l][wv][hi][ks][nt][lm][e]  (halves)
//   idx = (l*8+wv)*32768 + hi*16384 + ks*512 + nt*256 + lm*8 + e
__global__ void prep_fused(const float* __restrict__ lat, const float* __restrict__ W0,
                           const float* __restrict__ b0,
                           const float* __restrict__ W1, const float* __restrict__ W2,
                           float* __restrict__ latw, _Float16* __restrict__ ws) {
    __shared__ float sl[H];
    if (blockIdx.x < 1024) {
        const int id = blockIdx.x * 512 + threadIdx.x;   // 0 .. 524287
        const int l = id >> 18;
        const int rem = id & 0x3FFFF;                    // k*512 + n
        const int k = rem >> 9, n = rem & 511;
        const float w = (l == 0 ? W1 : W2)[rem];
        const int ks = k >> 4, hi = (k >> 3) & 1, e = k & 7;
        const int wv = n >> 6, nt = (n >> 5) & 1, lm = n & 31;
        ws[(size_t)(l * 8 + wv) * 32768 + hi * 16384 + ks * 512 + nt * 256 + lm * 8 + e]
            = (_Float16)w;
    } else {
        const int b = blockIdx.x - 1024;
        const int j = threadIdx.x;
        sl[j] = lat[b * H + j];
        __syncthreads();
        float acc = b0[j];
#pragma unroll 8
        for (int d = 0; d < H; ++d) acc += sl[d] * W0[d * H + j];
        latw[b * H + j] = acc;
    }
}

// ---- main fused kernel ----
// R8: forced W-prefetch, WAR-race fixed. R7's NaN: issue-before-compute
// into slot (ks+3)%3 == ks%3 put an in-flight load's destination under
// the MFMA's source registers (vmcnt(6) deliberately didn't cover it).
// Now: wait vmcnt(4) -> sched_barrier(0) -> compute(ks) -> THEN issue
// ks+3 into the just-consumed slot. Register-level WAR is program-ordered;
// counted waits stay >0 mid-loop (T4). W addressing: uniform SGPR base +
// ks*1024B (SALU) + loop-constant lane voffset + offset:512 imm.
// A: 2-deep compiler-managed ds_read queue (budget: ~60 VGPR + 64 AGPR
// <= 128 -> 4 waves/SIMD, 2 blocks/CU preserved).
__global__ __launch_bounds__(512, 4) void mesh_main(
    const float* __restrict__ W0, const float* __restrict__ b1,
    const float* __restrict__ b2, const float* __restrict__ W3,
    const float* __restrict__ b3, const float* __restrict__ latw,
    const _Float16* __restrict__ wsB, float* __restrict__ out) {

    __shared__ _Float16 hbuf2[4096 * 8];          // 64 KB, fragment-major h
    __shared__ float lwbuf[2 * H];                // 4 KB
    __shared__ float partials[8][MTILE];          // 2 KB  -> 70 KB total

    const int tid = threadIdx.x;
    const int wave = tid >> 6, lane = tid & 63;
    const int lm = lane & 31, hi = lane >> 5;
    const int uwave = __builtin_amdgcn_readfirstlane(wave);  // force SGPR
    const int bi = blockIdx.x;
    const int b = bi >> 12;
    const int p0 = (bi & 4095) << 6;              // 64 rows per block (fixed x,y)
    const float c0 = -1.2f + (float)(p0 >> 12) * STEPC;
    const float c1 = -1.2f + (float)((p0 >> 6) & 63) * STEPC;

    // ---- layer 0, phase A: lw[j] = latw + c0*W0x + c1*W0y; w2c[j] = W0z ----
    {
        const int j = tid;
        const float lwv = latw[b * H + j]
                        + c0 * W0[(H + 0) * H + j]
                        + c1 * W0[(H + 1) * H + j];
        floatx2 v;
        v[0] = lwv;
        v[1] = W0[(H + 2) * H + j];
        *(floatx2*)&lwbuf[2 * j] = v;
    }
    __syncthreads();

    // ---- layer 0, phase B: row m = lane; regions g = wave*8+s ----
    {
        const float c2v = -1.2f + (float)lane * STEPC;
#pragma unroll
        for (int s = 0; s < 8; ++s) {
            const int g = wave * 8 + s;
            const floatx4* lp = (const floatx4*)&lwbuf[g * 16];  // broadcast reads
            half8 hv;
#pragma unroll
            for (int i = 0; i < 4; ++i) {
                const floatx4 pv = lp[i];          // (lw, w2c, lw, w2c)
                hv[2 * i + 0] = (_Float16)silu_f(pv[0] + c2v * pv[1]);
                hv[2 * i + 1] = (_Float16)silu_f(pv[2] + c2v * pv[3]);
            }
            *(half8*)&hbuf2[(g * 64 + lane) * 8] = hv;
        }
    }

    // per-lane bases
    const _Float16* hb = hbuf2 + hi * 512 + lm * 8;      // A: LDS base, imm offsets
    const int vWoffB = hi * 32768 + lm * 16;             // W: loop-constant byte voffset

    floatx16 acc[2][2];

    auto zero_acc = [&]() {
#pragma unroll
        for (int mb = 0; mb < 2; ++mb)
#pragma unroll
            for (int nt = 0; nt < 2; ++nt)
#pragma unroll
                for (int r = 0; r < 16; ++r) acc[mb][nt][r] = 0.f;
    };

    // asm-pinned W-fragment load pair: saddr uniform, voffset constant, imm nt
    auto issueW = [&](const _Float16* base, int ks, half8 (&wf)[2]) {
        const _Float16* sp = base + ks * 512;            // uniform (SALU add)
        asm volatile("global_load_dwordx4 %0, %2, %3\n\t"
                     "global_load_dwordx4 %1, %2, %3 offset:512"
                     : "=v"(wf[0]), "=v"(wf[1])
                     : "v"(vWoffB), "s"(sp)
                     : "memory");
    };

    auto loadA = [&](int ks, half8 (&a)[2]) {
        const _Float16* hp = hb + ks * 1024;
        a[0] = *(const half8*)(hp);            // mb=0, pure offset-imm ds_read
        a[1] = *(const half8*)(hp + 256);      // mb=1
    };

    auto compute = [&](half8 (&wf)[2], half8 (&a)[2]) {
#pragma unroll
        for (int nt = 0; nt < 2; ++nt)
#pragma unroll
            for (int mb = 0; mb < 2; ++mb)
                acc[mb][nt] = __builtin_amdgcn_mfma_f32_32x32x16_f16(wf[nt], a[mb], acc[mb][nt], 0, 0, 0);
    };

    // K-loop: 3-deep forced W queue (issue AFTER consume: no WAR race),
    // counted vmcnt (never 0 mid-loop), 2-deep compiler-managed A queue.
    auto run_gemm = [&](const _Float16* base) {
        half8 Wq[3][2];
        half8 Aq[2][2];
        issueW(base, 0, Wq[0]);
        issueW(base, 1, Wq[1]);
        issueW(base, 2, Wq[2]);
        loadA(0, Aq[0]);
        loadA(1, Aq[1]);
#pragma unroll
        for (int ks = 0; ks < 32; ++ks) {       // fully unrolled, static indices
            // in flight: pairs for ks .. min(ks+2,31); wait until ks's pair lands
            if (ks <= 29)      asm volatile("s_waitcnt vmcnt(4)" ::: "memory");
            else if (ks == 30) asm volatile("s_waitcnt vmcnt(2)" ::: "memory");
            else               asm volatile("s_waitcnt vmcnt(0)" ::: "memory");
            __builtin_amdgcn_sched_barrier(0);
            compute(Wq[ks % 3], Aq[ks % 2]);
            if (ks + 3 < 32) issueW(base, ks + 3, Wq[ks % 3]);   // slot just consumed
            if (ks + 2 < 32) loadA(ks + 2, Aq[ks % 2]);          // compiler-ordered
        }
    };

    const _Float16* wbase0 = wsB + (size_t)uwave * 32768;         // GEMM1 (W1)
    const _Float16* wbase1 = wsB + (size_t)(8 + uwave) * 32768;   // GEMM2 (W2)

    // ---- GEMM 1 ----
    zero_acc();
    __syncthreads();             // h0 ready
    run_gemm(wbase0);
    __syncthreads();             // all waves done reading h0
    // writeback h1 = silu(acc + b1): lane owns, per (mb,nt,g), 4 consecutive
    // n = wave*64 + nt*32 + g*8 + hi*4 .. +3 at row m = mb*32+lm -> b64 writes
    {
        _Float16* wb = hbuf2 + (wave * 8) * 512 + lm * 8 + hi * 4;
        floatx4 b1v[2][4];
#pragma unroll
        for (int nt = 0; nt < 2; ++nt)
#pragma unroll
            for (int g = 0; g < 4; ++g)
                b1v[nt][g] = *(const floatx4*)&b1[wave * 64 + nt * 32 + g * 8 + hi * 4];
#pragma unroll
        for (int mb = 0; mb < 2; ++mb)
#pragma unroll
            for (int nt = 0; nt < 2; ++nt)
#pragma unroll
                for (int g = 0; g < 4; ++g) {
                    half4_t hv;
#pragma unroll
                    for (int j = 0; j < 4; ++j)
                        hv[j] = (_Float16)silu_f(acc[mb][nt][g * 4 + j] + b1v[nt][g][j]);
                    *(half4_t*)(wb + (nt * 4 + g) * 512 + mb * 256) = hv;
                }
    }

    // ---- GEMM 2 ----
    zero_acc();
    __syncthreads();             // h1 ready
    run_gemm(wbase1);

    // ---- final layer: out = silu(acc + b2) @ W3 + b3, fp32 VALU ----
    {
        floatx4 b2v[2][4], w3v[2][4];
#pragma unroll
        for (int nt = 0; nt < 2; ++nt)
#pragma unroll
            for (int g = 0; g < 4; ++g) {
                const int n0 = wave * 64 + nt * 32 + g * 8 + hi * 4;
                b2v[nt][g] = *(const floatx4*)&b2[n0];
                w3v[nt][g] = *(const floatx4*)&W3[n0];
            }
#pragma unroll
        for (int mb = 0; mb < 2; ++mb) {
            float sum = 0.f;
#pragma unroll
            for (int nt = 0; nt < 2; ++nt)
#pragma unroll
                for (int g = 0; g < 4; ++g)
#pragma unroll
                    for (int j = 0; j < 4; ++j)
                        sum += silu_f(acc[mb][nt][g * 4 + j] + b2v[nt][g][j]) * w3v[nt][g][j];
            sum += __shfl_xor(sum, 32);        // combine hi halves (same m)
            if (hi == 0) partials[wave][mb * 32 + lm] = sum;
        }
    }
    __syncthreads();
    if (tid < MTILE) {
        float o = b3[0];
#pragma unroll
        for (int w = 0; w < 8; ++w) o += partials[w][tid];
        out[(size_t)bi * MTILE + tid] = o;
    }
}

extern "C" void kernel_launch(void* const* d_in, const int* in_sizes, int n_in,
                              void* d_out, int out_size, void* d_ws, size_t ws_size,
                              hipStream_t stream) {
    const float* lat = (const float*)d_in[0];
    const float* W0  = (const float*)d_in[1];
    const float* b0  = (const float*)d_in[2];
    const float* W1  = (const float*)d_in[3];
    const float* b1  = (const float*)d_in[4];
    const float* W2  = (const float*)d_in[5];
    const float* b2  = (const float*)d_in[6];
    const float* W3  = (const float*)d_in[7];
    const float* b3  = (const float*)d_in[8];
    float* out = (float*)d_out;

    float* latw = (float*)d_ws;                               // 4 KB
    _Float16* wsB = (_Float16*)((char*)d_ws + 4096);          // 1 MB

    prep_fused<<<1026, 512, 0, stream>>>(lat, W0, b0, W1, W2, latw, wsB);
    mesh_main<<<NBLK, 512, 0, stream>>>(W0, b1, b2, W3, b3, latw, wsB, out);
}